// Round 1
// 176.480 us; speedup vs baseline: 1.0019x; 1.0019x over previous
//
#include <hip/hip_runtime.h>

#define NBATCH 128
#define NANCH  8732
#define NCLS   21
#define SUBS   8
#define SUBLEN 1092                    // 7*1092 + 1088 = 8732
#define ROUNDS 5                       // ceil(1092/256)

// ws: float4 partial[NBATCH * SUBS] -> 128*8*16 = 16384 bytes
// partial = { loc_sum, con_sum_all, con_sum_pos, pos_count }

// ---------------------------------------------------------------- helpers
__device__ __forceinline__ float waveReduceF(float v) {
    #pragma unroll
    for (int o = 32; o > 0; o >>= 1) v += __shfl_down(v, o, 64);
    return v;
}
__device__ __forceinline__ unsigned waveReduceU(unsigned v) {
    #pragma unroll
    for (int o = 32; o > 0; o >>= 1) v += __shfl_down(v, o, 64);
    return v;
}

// cross entropy for the cold mining path only
__device__ __forceinline__ float con_from_row(const float* __restrict__ row, int lbl) {
    float m = row[0];
    #pragma unroll
    for (int c = 1; c < NCLS; ++c) m = fmaxf(m, row[c]);
    float s = 0.f;
    #pragma unroll
    for (int c = 0; c < NCLS; ++c) s += __expf(row[c] - m);
    return m + __logf(s) - row[lbl];
}

// async global -> LDS, 16 bytes per lane. LDS dest must be the wave-uniform
// base; HW writes base + lane*16 (guide §5: global_load_lds semantics).
__device__ __forceinline__ void gload_lds16(const float4* g, float4* l) {
    __builtin_amdgcn_global_load_lds(
        (const __attribute__((address_space(1))) void*)g,
        (__attribute__((address_space(3))) void*)l,
        16, 0, 0);
}

// ---------------------------------------------------------------- kernel 1
// 1024 blocks = 128 batches x 8 contiguous sub-ranges of 1092 anchors.
// Per round: cooperatively stage 256 rows (21504 B = 1344 float4, 16B-aligned
// at the round base) into LDS with coalesced global_load_lds width=16, then
// each lane consumes its 84 B row from LDS (stride 21 dwords -> gcd(21,32)=1,
// conflict-free b32 reads). This removes the ~5x L1-transaction amplification
// of the previous per-lane strided float4 row loads.
__global__ __launch_bounds__(256) void anchor_kernel(
    const float*  __restrict__ loc_out,   // [B,A,4]
    const float*  __restrict__ cls_out,   // [B,A,C]
    const float*  __restrict__ loc_lab,   // [B,A,4]
    const int*    __restrict__ labels,    // [B,A]
    float4* __restrict__ partial)         // [NBATCH*SUBS]
{
    __shared__ float ldsrow[256 * NCLS];  // 21504 B

    const int bid  = blockIdx.x;
    const int b    = bid >> 3;
    const int sub  = bid & 7;
    const int tid  = threadIdx.x;
    const int start = sub * SUBLEN;
    const int len   = (sub == 7) ? (NANCH - 7 * SUBLEN) : SUBLEN;   // 1088 or 1092
    const int wbase = (tid >> 6) << 6;    // wave's first tid (uniform per wave)

    float loc_s = 0.f, all_s = 0.f, pos_s = 0.f;
    unsigned pc = 0;

    for (int r = 0; r < ROUNDS; ++r) {
        const int al    = r * 256 + tid;
        const bool valid = al < len;
        const int nA    = min(256, len - r * 256);        // 256 .. 68/64
        const int nF4   = (nA * NCLS) >> 2;               // nA%4==0 -> exact

        // round base: (b*8732 + sub*1092 + r*256)*84 bytes, all terms %16==0
        const size_t rbase = ((size_t)b * NANCH + start + r * 256) * NCLS;
        const float4* gsrc = reinterpret_cast<const float4*>(cls_out + rbase);

        // coalesced per-lane loads (4B / 16B strides) issued early
        int lbl = 0; float4 lo4 = {}; float4 ll4 = {};
        if (valid) {
            const size_t ba = (size_t)b * NANCH + start + al;
            lbl = labels[ba];
            lo4 = ((const float4*)loc_out)[ba];
            ll4 = ((const float4*)loc_lab)[ba];
        }

        if (r) __syncthreads();           // prev-round LDS reads done
        float4* lbase = (float4*)ldsrow;
        #pragma unroll
        for (int i = 0; i < 6; ++i) {
            const int idx = i * 256 + tid;
            if (idx < nF4)
                gload_lds16(gsrc + idx, lbase + i * 256 + wbase);
        }
        __syncthreads();                  // vmcnt(0) drained by barrier

        if (valid) {
            const float* __restrict__ row = ldsrow + tid * NCLS;
            float f[NCLS];
            #pragma unroll
            for (int c = 0; c < NCLS; ++c) f[c] = row[c];

            float m = f[0];
            #pragma unroll
            for (int c = 1; c < NCLS; ++c) m = fmaxf(m, f[c]);
            float s = 0.f;
            #pragma unroll
            for (int c = 0; c < NCLS; ++c) s += __expf(f[c] - m);

            const float tgt = row[lbl];   // one dynamic ds_read, replaces
                                          // the 20x cmp+cndmask chain
            const float con = m + __logf(s) - tgt;
            all_s += con;
            if (lbl > 0) {
                pos_s += con;
                pc++;
                float d0 = lo4.x - ll4.x, d1 = lo4.y - ll4.y,
                      d2 = lo4.z - ll4.z, d3 = lo4.w - ll4.w;
                float a0 = fabsf(d0), a1 = fabsf(d1), a2 = fabsf(d2), a3 = fabsf(d3);
                loc_s += ((a0 < 1.f) ? 0.5f * d0 * d0 : (a0 - 0.5f))
                       + ((a1 < 1.f) ? 0.5f * d1 * d1 : (a1 - 0.5f))
                       + ((a2 < 1.f) ? 0.5f * d2 * d2 : (a2 - 0.5f))
                       + ((a3 < 1.f) ? 0.5f * d3 * d3 : (a3 - 0.5f));
            }
        }
    }

    // block reduce: wave shuffle then tiny LDS
    loc_s = waveReduceF(loc_s);
    all_s = waveReduceF(all_s);
    pos_s = waveReduceF(pos_s);
    pc    = waveReduceU(pc);

    __shared__ float sL[4], sA[4], sP[4];
    __shared__ unsigned sC[4];
    const int w = tid >> 6, lane = tid & 63;
    if (lane == 0) { sL[w] = loc_s; sA[w] = all_s; sP[w] = pos_s; sC[w] = pc; }
    __syncthreads();
    if (tid == 0) {
        float L = sL[0] + sL[1] + sL[2] + sL[3];
        float S = sA[0] + sA[1] + sA[2] + sA[3];
        float P = sP[0] + sP[1] + sP[2] + sP[3];
        unsigned C = sC[0] + sC[1] + sC[2] + sC[3];
        partial[bid] = make_float4(L, S, P, (float)C);
    }
}

// ---------------------------------------------------------------- kernel 2
// Single block. Threads 0..127 each own a batch: reduce the 8 partials,
// apply mining formula (hot path: all-ones neg_mask), block-reduce the mean.
__global__ __launch_bounds__(256) void finalize_kernel(
    const float* __restrict__ cls_out,
    const int*   __restrict__ labels,
    const float4* __restrict__ partial,
    float* __restrict__ out)
{
    const int tid = threadIdx.x;

    __shared__ float sLoc[NBATCH], sPos[NBATCH], sCnt[NBATCH], sConl[NBATCH];
    __shared__ unsigned sK[NBATCH];
    __shared__ unsigned nflag;
    if (tid == 0) nflag = 0;
    __syncthreads();

    if (tid < NBATCH) {
        float loc = 0.f, all = 0.f, pos = 0.f, cnt = 0.f;
        #pragma unroll
        for (int c = 0; c < SUBS; ++c) {
            float4 p = partial[tid * SUBS + c];
            loc += p.x; all += p.y; pos += p.z; cnt += p.w;
        }
        unsigned k = 3u * (unsigned)cnt;
        if (k > NANCH) k = NANCH;
        if (k == 0u) k = 3u;
        sLoc[tid] = loc; sPos[tid] = pos; sCnt[tid] = cnt;
        sConl[tid] = all + pos;          // hot path: neg_mask all-ones
        if (k < NANCH) { sK[tid] = k; atomicAdd(&nflag, 1u); }
        else sK[tid] = 0u;
    }
    __syncthreads();

    if (nflag) {
        // cold general path: exact top-k of con_neg per flagged batch
        __shared__ float    rF[256];
        __shared__ unsigned rU[256];
        for (int b2 = 0; b2 < NBATCH; ++b2) {
            unsigned k = sK[b2];
            if (!k) continue;

            auto count_gt = [&](float t) -> unsigned {
                unsigned cc = 0;
                for (int an = tid; an < NANCH; an += 256) {
                    size_t ba = (size_t)b2 * NANCH + an;
                    int lbl = labels[ba];
                    if (lbl > 0) continue;
                    float con = con_from_row(cls_out + ba * NCLS, lbl);
                    if (con > t) cc++;
                }
                rU[tid] = cc; __syncthreads();
                for (int o = 128; o > 0; o >>= 1) {
                    if (tid < o) rU[tid] += rU[tid + o];
                    __syncthreads();
                }
                unsigned r = rU[0]; __syncthreads();
                return r;
            };

            unsigned cpos = count_gt(0.0f);
            float negpart = 0.f;

            if (k <= cpos) {
                unsigned lo = 0u, hi = 0x7F800000u;
                while (hi - lo > 1u) {
                    unsigned mid = lo + (hi - lo) / 2u;
                    unsigned cc = count_gt(__uint_as_float(mid));
                    if (cc >= k) lo = mid; else hi = mid;
                }
                float v = __uint_as_float(hi);   // k-th largest value
                float ss = 0.f; unsigned c1 = 0;
                for (int an = tid; an < NANCH; an += 256) {
                    size_t ba = (size_t)b2 * NANCH + an;
                    int lbl = labels[ba];
                    if (lbl > 0) continue;
                    float con = con_from_row(cls_out + ba * NCLS, lbl);
                    if (con > v) { ss += con; c1++; }
                }
                rF[tid] = ss; rU[tid] = c1; __syncthreads();
                for (int o = 128; o > 0; o >>= 1) {
                    if (tid < o) { rF[tid] += rF[tid + o]; rU[tid] += rU[tid + o]; }
                    __syncthreads();
                }
                negpart = rF[0] + (float)(k - rU[0]) * v;
                __syncthreads();
            } else {
                if (tid == 0) {
                    float np = 0.f;
                    unsigned mrem = k - cpos;
                    for (int an = 0; an < NANCH; ++an) {
                        size_t ba = (size_t)b2 * NANCH + an;
                        int lbl = labels[ba];
                        float con = con_from_row(cls_out + ba * NCLS, lbl);
                        float cneg = (lbl > 0) ? 0.f : con;
                        if (cneg > 0.f) np += con;
                        else if (mrem > 0u) { np += con; mrem--; }
                    }
                    rF[0] = np;
                }
                __syncthreads();
                negpart = rF[0];
                __syncthreads();
            }

            if (tid == 0) sConl[b2] = sPos[b2] + negpart;
            __syncthreads();
        }
    }

    // final mean over batches
    float t = 0.f;
    if (tid < NBATCH) {
        float denom = (sCnt[tid] != 0.f) ? sCnt[tid] : 1.f;
        t = (sLoc[tid] + sConl[tid]) / denom;
    }
    t = waveReduceF(t);
    __shared__ float sW[4];
    const int w = tid >> 6, lane = tid & 63;
    if (lane == 0) sW[w] = t;
    __syncthreads();
    if (tid == 0) out[0] = (sW[0] + sW[1] + sW[2] + sW[3]) * (1.f / NBATCH);
}

// ---------------------------------------------------------------- launch
extern "C" void kernel_launch(void* const* d_in, const int* in_sizes, int n_in,
                              void* d_out, int out_size, void* d_ws, size_t ws_size,
                              hipStream_t stream) {
    const float* loc_out = (const float*)d_in[0];
    const float* cls_out = (const float*)d_in[1];
    const float* loc_lab = (const float*)d_in[2];
    const int*   labels  = (const int*)d_in[3];
    float* out = (float*)d_out;
    float4* partial = (float4*)d_ws;   // 128*8*16 = 16384 B of ws

    anchor_kernel<<<NBATCH * SUBS, 256, 0, stream>>>(loc_out, cls_out, loc_lab, labels, partial);
    finalize_kernel<<<1, 256, 0, stream>>>(cls_out, labels, partial, out);
}

// Round 2
// 174.548 us; speedup vs baseline: 1.0130x; 1.0111x over previous
//
#include <hip/hip_runtime.h>

#define NBATCH 128
#define NANCH  8732
#define NCLS   21
#define TPB    512
#define SUBS   18                      // ceil(8732/512); 17*512=8704, last block 28

// ws: float4 partial[NBATCH * SUBS] -> 128*18*16 = 36864 bytes
// partial = { loc_sum, con_sum_all, con_sum_pos, pos_count }

// ---------------------------------------------------------------- helpers
__device__ __forceinline__ float waveReduceF(float v) {
    #pragma unroll
    for (int o = 32; o > 0; o >>= 1) v += __shfl_down(v, o, 64);
    return v;
}
__device__ __forceinline__ unsigned waveReduceU(unsigned v) {
    #pragma unroll
    for (int o = 32; o > 0; o >>= 1) v += __shfl_down(v, o, 64);
    return v;
}

// cross entropy for the cold mining path only
__device__ __forceinline__ float con_from_row(const float* __restrict__ row, int lbl) {
    float m = row[0];
    #pragma unroll
    for (int c = 1; c < NCLS; ++c) m = fmaxf(m, row[c]);
    float s = 0.f;
    #pragma unroll
    for (int c = 0; c < NCLS; ++c) s += __expf(row[c] - m);
    return m + __logf(s) - row[lbl];
}

// ---------------------------------------------------------------- kernel 1
// Latency-hiding restructure: ONE anchor per thread, no round loop, no LDS
// staging, no mid-kernel barriers. grid = 18 x 128 = 2304 blocks of 512
// threads -> ~9 blocks/CU issued, 4 co-resident (32 waves/CU) with VGPR<=64.
// Each lane issues its whole independent load set (label + 5xfloat4 row +
// dependent tgt gather + 2xfloat4 loc) in one burst; waves hide each other's
// HBM latency. Previous 5-round structure at VGPR=24 serialized every load.
__global__ __launch_bounds__(TPB, 8) void anchor_kernel(
    const float*  __restrict__ loc_out,   // [B,A,4]
    const float*  __restrict__ cls_out,   // [B,A,C]
    const float*  __restrict__ loc_lab,   // [B,A,4]
    const int*    __restrict__ labels,    // [B,A]
    float4* __restrict__ partial)         // [NBATCH*SUBS]
{
    const int b   = blockIdx.y;
    const int s   = blockIdx.x;
    const int tid = threadIdx.x;
    const int a   = s * TPB + tid;

    float loc_s = 0.f, all_s = 0.f, pos_s = 0.f;
    unsigned pc = 0;

    if (a < NANCH) {
        const size_t ba = (size_t)b * NANCH + a;
        const float* __restrict__ row = cls_out + ba * NCLS;

        const int   lbl = labels[ba];
        const float4 r0 = *(const float4*)(row +  0);
        const float4 r1 = *(const float4*)(row +  4);
        const float4 r2 = *(const float4*)(row +  8);
        const float4 r3 = *(const float4*)(row + 12);
        const float4 r4 = *(const float4*)(row + 16);
        const float  r5 = row[20];
        const float4 lo4 = ((const float4*)loc_out)[ba];
        const float4 ll4 = ((const float4*)loc_lab)[ba];
        const float tgt = row[lbl];       // L1/L2 hit; replaces 20x cndmask

        float m = r0.x;
        m = fmaxf(m, r0.y); m = fmaxf(m, r0.z); m = fmaxf(m, r0.w);
        m = fmaxf(m, r1.x); m = fmaxf(m, r1.y); m = fmaxf(m, r1.z); m = fmaxf(m, r1.w);
        m = fmaxf(m, r2.x); m = fmaxf(m, r2.y); m = fmaxf(m, r2.z); m = fmaxf(m, r2.w);
        m = fmaxf(m, r3.x); m = fmaxf(m, r3.y); m = fmaxf(m, r3.z); m = fmaxf(m, r3.w);
        m = fmaxf(m, r4.x); m = fmaxf(m, r4.y); m = fmaxf(m, r4.z); m = fmaxf(m, r4.w);
        m = fmaxf(m, r5);

        float sum = __expf(r0.x - m) + __expf(r0.y - m) + __expf(r0.z - m) + __expf(r0.w - m)
                  + __expf(r1.x - m) + __expf(r1.y - m) + __expf(r1.z - m) + __expf(r1.w - m)
                  + __expf(r2.x - m) + __expf(r2.y - m) + __expf(r2.z - m) + __expf(r2.w - m)
                  + __expf(r3.x - m) + __expf(r3.y - m) + __expf(r3.z - m) + __expf(r3.w - m)
                  + __expf(r4.x - m) + __expf(r4.y - m) + __expf(r4.z - m) + __expf(r4.w - m)
                  + __expf(r5 - m);

        const float con = m + __logf(sum) - tgt;
        all_s = con;
        if (lbl > 0) {
            pos_s = con;
            pc = 1;
            float d0 = lo4.x - ll4.x, d1 = lo4.y - ll4.y,
                  d2 = lo4.z - ll4.z, d3 = lo4.w - ll4.w;
            float a0 = fabsf(d0), a1 = fabsf(d1), a2 = fabsf(d2), a3 = fabsf(d3);
            loc_s = ((a0 < 1.f) ? 0.5f * d0 * d0 : (a0 - 0.5f))
                  + ((a1 < 1.f) ? 0.5f * d1 * d1 : (a1 - 0.5f))
                  + ((a2 < 1.f) ? 0.5f * d2 * d2 : (a2 - 0.5f))
                  + ((a3 < 1.f) ? 0.5f * d3 * d3 : (a3 - 0.5f));
        }
    }

    // block reduce: wave shuffle then tiny LDS (8 waves)
    loc_s = waveReduceF(loc_s);
    all_s = waveReduceF(all_s);
    pos_s = waveReduceF(pos_s);
    pc    = waveReduceU(pc);

    __shared__ float sL[8], sA[8], sP[8];
    __shared__ unsigned sC[8];
    const int w = tid >> 6, lane = tid & 63;
    if (lane == 0) { sL[w] = loc_s; sA[w] = all_s; sP[w] = pos_s; sC[w] = pc; }
    __syncthreads();
    if (tid == 0) {
        float L = 0.f, S = 0.f, P = 0.f; unsigned C = 0;
        #pragma unroll
        for (int i = 0; i < 8; ++i) { L += sL[i]; S += sA[i]; P += sP[i]; C += sC[i]; }
        partial[b * SUBS + s] = make_float4(L, S, P, (float)C);
    }
}

// ---------------------------------------------------------------- kernel 2
// Single block. Threads 0..127 each own a batch: reduce the 18 partials,
// apply mining formula (hot path: all-ones neg_mask), block-reduce the mean.
__global__ __launch_bounds__(256) void finalize_kernel(
    const float* __restrict__ cls_out,
    const int*   __restrict__ labels,
    const float4* __restrict__ partial,
    float* __restrict__ out)
{
    const int tid = threadIdx.x;

    __shared__ float sLoc[NBATCH], sPos[NBATCH], sCnt[NBATCH], sConl[NBATCH];
    __shared__ unsigned sK[NBATCH];
    __shared__ unsigned nflag;
    if (tid == 0) nflag = 0;
    __syncthreads();

    if (tid < NBATCH) {
        float loc = 0.f, all = 0.f, pos = 0.f, cnt = 0.f;
        #pragma unroll
        for (int c = 0; c < SUBS; ++c) {
            float4 p = partial[tid * SUBS + c];
            loc += p.x; all += p.y; pos += p.z; cnt += p.w;
        }
        unsigned k = 3u * (unsigned)cnt;
        if (k > NANCH) k = NANCH;
        if (k == 0u) k = 3u;
        sLoc[tid] = loc; sPos[tid] = pos; sCnt[tid] = cnt;
        sConl[tid] = all + pos;          // hot path: neg_mask all-ones
        if (k < NANCH) { sK[tid] = k; atomicAdd(&nflag, 1u); }
        else sK[tid] = 0u;
    }
    __syncthreads();

    if (nflag) {
        // cold general path: exact top-k of con_neg per flagged batch
        __shared__ float    rF[256];
        __shared__ unsigned rU[256];
        for (int b2 = 0; b2 < NBATCH; ++b2) {
            unsigned k = sK[b2];
            if (!k) continue;

            auto count_gt = [&](float t) -> unsigned {
                unsigned cc = 0;
                for (int an = tid; an < NANCH; an += 256) {
                    size_t ba = (size_t)b2 * NANCH + an;
                    int lbl = labels[ba];
                    if (lbl > 0) continue;
                    float con = con_from_row(cls_out + ba * NCLS, lbl);
                    if (con > t) cc++;
                }
                rU[tid] = cc; __syncthreads();
                for (int o = 128; o > 0; o >>= 1) {
                    if (tid < o) rU[tid] += rU[tid + o];
                    __syncthreads();
                }
                unsigned r = rU[0]; __syncthreads();
                return r;
            };

            unsigned cpos = count_gt(0.0f);
            float negpart = 0.f;

            if (k <= cpos) {
                unsigned lo = 0u, hi = 0x7F800000u;
                while (hi - lo > 1u) {
                    unsigned mid = lo + (hi - lo) / 2u;
                    unsigned cc = count_gt(__uint_as_float(mid));
                    if (cc >= k) lo = mid; else hi = mid;
                }
                float v = __uint_as_float(hi);   // k-th largest value
                float ss = 0.f; unsigned c1 = 0;
                for (int an = tid; an < NANCH; an += 256) {
                    size_t ba = (size_t)b2 * NANCH + an;
                    int lbl = labels[ba];
                    if (lbl > 0) continue;
                    float con = con_from_row(cls_out + ba * NCLS, lbl);
                    if (con > v) { ss += con; c1++; }
                }
                rF[tid] = ss; rU[tid] = c1; __syncthreads();
                for (int o = 128; o > 0; o >>= 1) {
                    if (tid < o) { rF[tid] += rF[tid + o]; rU[tid] += rU[tid + o]; }
                    __syncthreads();
                }
                negpart = rF[0] + (float)(k - rU[0]) * v;
                __syncthreads();
            } else {
                if (tid == 0) {
                    float np = 0.f;
                    unsigned mrem = k - cpos;
                    for (int an = 0; an < NANCH; ++an) {
                        size_t ba = (size_t)b2 * NANCH + an;
                        int lbl = labels[ba];
                        float con = con_from_row(cls_out + ba * NCLS, lbl);
                        float cneg = (lbl > 0) ? 0.f : con;
                        if (cneg > 0.f) np += con;
                        else if (mrem > 0u) { np += con; mrem--; }
                    }
                    rF[0] = np;
                }
                __syncthreads();
                negpart = rF[0];
                __syncthreads();
            }

            if (tid == 0) sConl[b2] = sPos[b2] + negpart;
            __syncthreads();
        }
    }

    // final mean over batches
    float t = 0.f;
    if (tid < NBATCH) {
        float denom = (sCnt[tid] != 0.f) ? sCnt[tid] : 1.f;
        t = (sLoc[tid] + sConl[tid]) / denom;
    }
    t = waveReduceF(t);
    __shared__ float sW[4];
    const int w = tid >> 6, lane = tid & 63;
    if (lane == 0) sW[w] = t;
    __syncthreads();
    if (tid == 0) out[0] = (sW[0] + sW[1] + sW[2] + sW[3]) * (1.f / NBATCH);
}

// ---------------------------------------------------------------- launch
extern "C" void kernel_launch(void* const* d_in, const int* in_sizes, int n_in,
                              void* d_out, int out_size, void* d_ws, size_t ws_size,
                              hipStream_t stream) {
    const float* loc_out = (const float*)d_in[0];
    const float* cls_out = (const float*)d_in[1];
    const float* loc_lab = (const float*)d_in[2];
    const int*   labels  = (const int*)d_in[3];
    float* out = (float*)d_out;
    float4* partial = (float4*)d_ws;   // 128*18*16 = 36864 B of ws

    dim3 grid(SUBS, NBATCH);
    anchor_kernel<<<grid, TPB, 0, stream>>>(loc_out, cls_out, loc_lab, labels, partial);
    finalize_kernel<<<1, 256, 0, stream>>>(cls_out, labels, partial, out);
}